// Round 12
// baseline (403.896 us; speedup 1.0000x reference)
//
#include <hip/hip_runtime.h>

#define N_NODES 50000
#define N_EDGES 600000
#define HID 128
#define N_GRAPHS 512
#define BN_EPS 1e-5f
#define INV_N (1.0f / 50000.0f)

typedef __attribute__((ext_vector_type(8))) short bf16x8;
typedef __attribute__((ext_vector_type(4))) float f32x4;

__device__ __forceinline__ unsigned short f2b(float f) {
    unsigned u = __float_as_uint(f);
    return (unsigned short)((u + 0x7FFFu + ((u >> 16) & 1u)) >> 16);
}
__device__ __forceinline__ float b2f(unsigned short h) {
    return __uint_as_float(((unsigned)h) << 16);
}

// ---------------------------------------------------------------------------
// prep: convert x -> bf16 | transpose+convert 6 weight mats | degree count
// ---------------------------------------------------------------------------
#define CONVX_BLOCKS 6250
#define WCONV_BLOCKS 384
#define DEG_BLOCKS   2344
__global__ __launch_bounds__(256) void prep_kernel(
    const float* __restrict__ x, const float* __restrict__ gw1, const float* __restrict__ gw2,
    const float* __restrict__ swl, const float* __restrict__ swr, const int* __restrict__ dst,
    unsigned short* __restrict__ x16, unsigned short* __restrict__ wt, int* __restrict__ deg)
{
    int b = blockIdx.x;
    int t = threadIdx.x;
    if (b < CONVX_BLOCKS) {
        int gid = b * 256 + t;
        int i = gid >> 5, l = gid & 31;
        if (i >= N_NODES) return;
        int c0 = l * 4;
        float4 v = *(const float4*)(x + (size_t)i * 128 + c0);
        ushort4 o;
        o.x = f2b(v.x); o.y = f2b(v.y); o.z = f2b(v.z); o.w = f2b(v.w);
        *(ushort4*)(x16 + (size_t)i * 128 + c0) = o;
    } else if (b < CONVX_BLOCKS + WCONV_BLOCKS) {
        int gid = (b - CONVX_BLOCKS) * 256 + t;   // < 6*16384
        int m = gid >> 14;
        int e = gid & 16383;
        int k = e >> 7;
        int n = e & 127;
        const float* src = (m == 0) ? gw1 : (m == 1) ? gw2 : (m == 2) ? swl
                         : (m == 3) ? swr : (m == 4) ? (swl + 16384) : (swr + 16384);
        wt[m * 16384 + n * 128 + k] = f2b(src[k * 128 + n]);
    } else {
        int e = (b - CONVX_BLOCKS - WCONV_BLOCKS) * 256 + t;
        if (e < N_EDGES) atomicAdd(&deg[dst[e]], 1);
    }
}

// ---------------------------------------------------------------------------
// alloc (per-block scan + atomic base) + gstart (binary search), fused
// ---------------------------------------------------------------------------
#define ALLOC_BLOCKS 196
__global__ __launch_bounds__(256) void alloc_kernel(int* __restrict__ cursor,
                                                    int* __restrict__ row_beg,
                                                    float* __restrict__ inv_deg,
                                                    int* __restrict__ total,
                                                    const int* __restrict__ batch,
                                                    int* __restrict__ gstart) {
    if (blockIdx.x >= ALLOC_BLOCKS) {
        int g = (blockIdx.x - ALLOC_BLOCKS) * 256 + threadIdx.x;
        if (g > N_GRAPHS) return;
        int lo = 0, hi = N_NODES;
        while (lo < hi) {
            int mid = (lo + hi) >> 1;
            if (batch[mid] < g) lo = mid + 1; else hi = mid;
        }
        gstart[g] = lo;
        return;
    }
    __shared__ int tmp[256];
    __shared__ int base;
    int i = blockIdx.x * 256 + threadIdx.x;
    int d = (i < N_NODES) ? cursor[i] : 0;
    tmp[threadIdx.x] = d;
    __syncthreads();
#pragma unroll
    for (int off = 1; off < 256; off <<= 1) {
        int v = (threadIdx.x >= off) ? tmp[threadIdx.x - off] : 0;
        __syncthreads();
        tmp[threadIdx.x] += v;
        __syncthreads();
    }
    if (threadIdx.x == 255) base = atomicAdd(total, tmp[255]);
    __syncthreads();
    if (i < N_NODES) {
        int b = base + tmp[threadIdx.x] - d;
        row_beg[i] = b;
        cursor[i] = b;
        inv_deg[i] = 1.0f / fmaxf((float)d, 1.0f);
    }
}

__global__ void csr_fill_kernel(const int* __restrict__ src, const int* __restrict__ dst,
                                int* __restrict__ cursor, int* __restrict__ csr_src, int nE) {
    int e = blockIdx.x * blockDim.x + threadIdx.x;
    if (e < nE) {
        int pos = atomicAdd(&cursor[dst[e]], 1);
        csr_src[pos] = src[e];
    }
}

// ---------------------------------------------------------------------------
// Fused GIN layer: per 16-row tile, stage A = x + sum_nbr(x) into LDS via
// direct gather, then Cb = bf16( relu(A@W1+b1) @ W2 + b2 ) + stats.
// Staging: 16 threads/row x 8 cols. MFMA: wave = 16 rows x 32 cols (swapped
// operands: thread owns row m16, cols colbase+ct*16+quad*4..+3).
// N_NODES % 16 == 0 -> no boundary checks.
// ---------------------------------------------------------------------------
__global__ __launch_bounds__(256) void gin_fused_kernel(
    const unsigned short* __restrict__ x16,
    const int* __restrict__ row_beg, const int* __restrict__ row_end,
    const int* __restrict__ csr_src,
    const unsigned short* __restrict__ W1t, const unsigned short* __restrict__ W2t,
    const float* __restrict__ b1, const float* __restrict__ b2,
    float* __restrict__ stats, unsigned short* __restrict__ Cb, int ntiles)
{
    __shared__ unsigned short As[16][136];
    __shared__ unsigned short T1[16][136];
    __shared__ float red[128];

    const int t = threadIdx.x;
    const int srow = t >> 4;
    const int sub = t & 15;
    const int sc0 = sub * 8;

    const int wave = t >> 6;
    const int lane = t & 63;
    const int m16 = lane & 15;
    const int quad = lane >> 4;
    const int k0 = quad * 8;
    const int colbase = wave * 32;

    bf16x8 w1f[2][4], w2f[2][4];
#pragma unroll
    for (int ct = 0; ct < 2; ct++) {
        int col = colbase + ct * 16 + m16;
#pragma unroll
        for (int kc = 0; kc < 4; kc++) {
            w1f[ct][kc] = *(const bf16x8*)(W1t + (size_t)col * 128 + kc * 32 + k0);
            w2f[ct][kc] = *(const bf16x8*)(W2t + (size_t)col * 128 + kc * 32 + k0);
        }
    }
    f32x4 bs1[2], bs2[2];
#pragma unroll
    for (int ct = 0; ct < 2; ct++) {
        bs1[ct] = *(const f32x4*)(b1 + colbase + ct * 16 + quad * 4);
        bs2[ct] = *(const f32x4*)(b2 + colbase + ct * 16 + quad * 4);
    }

    float psum[2][4], psq[2][4];
#pragma unroll
    for (int ct = 0; ct < 2; ct++)
#pragma unroll
        for (int r = 0; r < 4; r++) { psum[ct][r] = 0.f; psq[ct][r] = 0.f; }

    for (int tile = blockIdx.x; tile < ntiles; tile += gridDim.x) {
        int grow = tile * 16 + srow;
        int beg = row_beg[grow];
        int end = row_end[grow];
        bf16x8 own = *(const bf16x8*)(x16 + (size_t)grow * 128 + sc0);
        float acc[8];
#pragma unroll
        for (int j = 0; j < 8; j++) acc[j] = b2f((unsigned short)own[j]);

        int e = beg;
        for (; e + 3 < end; e += 4) {
            int s0 = csr_src[e], s1 = csr_src[e + 1], s2 = csr_src[e + 2], s3 = csr_src[e + 3];
            bf16x8 v0 = *(const bf16x8*)(x16 + (size_t)s0 * 128 + sc0);
            bf16x8 v1 = *(const bf16x8*)(x16 + (size_t)s1 * 128 + sc0);
            bf16x8 v2 = *(const bf16x8*)(x16 + (size_t)s2 * 128 + sc0);
            bf16x8 v3 = *(const bf16x8*)(x16 + (size_t)s3 * 128 + sc0);
#pragma unroll
            for (int j = 0; j < 8; j++)
                acc[j] += (b2f((unsigned short)v0[j]) + b2f((unsigned short)v1[j]))
                        + (b2f((unsigned short)v2[j]) + b2f((unsigned short)v3[j]));
        }
        for (; e < end; e++) {
            int s0 = csr_src[e];
            bf16x8 v0 = *(const bf16x8*)(x16 + (size_t)s0 * 128 + sc0);
#pragma unroll
            for (int j = 0; j < 8; j++) acc[j] += b2f((unsigned short)v0[j]);
        }

        __syncthreads();   // previous tile's LDS reads complete
        bf16x8 o;
#pragma unroll
        for (int j = 0; j < 8; j++) o[j] = (short)f2b(acc[j]);
        *(bf16x8*)&As[srow][sc0] = o;
        __syncthreads();

        // phase 1: A @ W1
        bf16x8 a[4];
#pragma unroll
        for (int kc = 0; kc < 4; kc++) a[kc] = *(const bf16x8*)&As[m16][kc * 32 + k0];
        f32x4 acc1[2];
        acc1[0] = (f32x4){0.f, 0.f, 0.f, 0.f};
        acc1[1] = (f32x4){0.f, 0.f, 0.f, 0.f};
#pragma unroll
        for (int kc = 0; kc < 4; kc++)
#pragma unroll
            for (int ct = 0; ct < 2; ct++)
                acc1[ct] = __builtin_amdgcn_mfma_f32_16x16x32_bf16(w1f[ct][kc], a[kc], acc1[ct], 0, 0, 0);

        // T1 = relu(acc1 + b1)
#pragma unroll
        for (int ct = 0; ct < 2; ct++) {
            f32x4 v = acc1[ct] + bs1[ct];
            ushort4 u;
            u.x = f2b(fmaxf(v[0], 0.f));
            u.y = f2b(fmaxf(v[1], 0.f));
            u.z = f2b(fmaxf(v[2], 0.f));
            u.w = f2b(fmaxf(v[3], 0.f));
            *(ushort4*)&T1[m16][colbase + ct * 16 + quad * 4] = u;
        }
        __syncthreads();

        // phase 2: T1 @ W2
        bf16x8 ta[4];
#pragma unroll
        for (int kc = 0; kc < 4; kc++) ta[kc] = *(const bf16x8*)&T1[m16][kc * 32 + k0];
        f32x4 acc2[2];
        acc2[0] = (f32x4){0.f, 0.f, 0.f, 0.f};
        acc2[1] = (f32x4){0.f, 0.f, 0.f, 0.f};
#pragma unroll
        for (int kc = 0; kc < 4; kc++)
#pragma unroll
            for (int ct = 0; ct < 2; ct++)
                acc2[ct] = __builtin_amdgcn_mfma_f32_16x16x32_bf16(w2f[ct][kc], ta[kc], acc2[ct], 0, 0, 0);

        int orow = tile * 16 + m16;
#pragma unroll
        for (int ct = 0; ct < 2; ct++) {
            f32x4 v = acc2[ct] + bs2[ct];
            int col = colbase + ct * 16 + quad * 4;
#pragma unroll
            for (int r = 0; r < 4; r++) { psum[ct][r] += v[r]; psq[ct][r] += v[r] * v[r]; }
            ushort4 u;
            u.x = f2b(v[0]); u.y = f2b(v[1]); u.z = f2b(v[2]); u.w = f2b(v[3]);
            *(ushort4*)(Cb + (size_t)orow * 128 + col) = u;
        }
    }

    // stats flush (waves own disjoint 32-col quarters)
#pragma unroll
    for (int ct = 0; ct < 2; ct++)
#pragma unroll
        for (int r = 0; r < 4; r++) {
#pragma unroll
            for (int mask = 1; mask <= 8; mask <<= 1) {
                psum[ct][r] += __shfl_xor(psum[ct][r], mask, 64);
                psq[ct][r]  += __shfl_xor(psq[ct][r], mask, 64);
            }
        }
    __syncthreads();
    if (m16 == 0) {
#pragma unroll
        for (int ct = 0; ct < 2; ct++)
#pragma unroll
            for (int r = 0; r < 4; r++)
                red[colbase + ct * 16 + quad * 4 + r] = psum[ct][r];
    }
    __syncthreads();
    if (t < 128) atomicAdd(&stats[t], red[t]);
    __syncthreads();
    if (m16 == 0) {
#pragma unroll
        for (int ct = 0; ct < 2; ct++)
#pragma unroll
            for (int r = 0; r < 4; r++)
                red[colbase + ct * 16 + quad * 4 + r] = psq[ct][r];
    }
    __syncthreads();
    if (t < 128) atomicAdd(&stats[128 + t], red[t]);
}

// ---------------------------------------------------------------------------
// Fused SAGE layer: stage A1 = mean_nbr(act(feat)) and A2 = act(feat[row])
// into LDS (act = relu(v*c+s), affine from stats_in), then
// Cb = bf16(A1@W1 + A2@W2 + bias) + stats_out.
// ---------------------------------------------------------------------------
__global__ __launch_bounds__(256) void sage_fused_kernel(
    const unsigned short* __restrict__ feat,
    const int* __restrict__ row_beg, const int* __restrict__ row_end,
    const int* __restrict__ csr_src,
    const float* __restrict__ stats_in, const float* __restrict__ gamma,
    const float* __restrict__ beta, const float* __restrict__ inv_deg,
    const unsigned short* __restrict__ W1t, const unsigned short* __restrict__ W2t,
    const float* __restrict__ bias,
    float* __restrict__ stats_out, unsigned short* __restrict__ Cb, int ntiles)
{
    __shared__ unsigned short As1[16][136];
    __shared__ unsigned short As2[16][136];
    __shared__ float red[128];

    const int t = threadIdx.x;
    const int srow = t >> 4;
    const int sub = t & 15;
    const int sc0 = sub * 8;

    const int wave = t >> 6;
    const int lane = t & 63;
    const int m16 = lane & 15;
    const int quad = lane >> 4;
    const int k0 = quad * 8;
    const int colbase = wave * 32;

    // BN affine for this thread's 8 staging columns
    float cc[8], ss[8];
#pragma unroll
    for (int j = 0; j < 8; j++) {
        int col = sc0 + j;
        float mu = stats_in[col] * INV_N;
        float var = stats_in[128 + col] * INV_N - mu * mu;
        float rs = rsqrtf(var + BN_EPS);
        float c = gamma[col] * rs;
        cc[j] = c;
        ss[j] = beta[col] - mu * c;
    }

    bf16x8 w1f[2][4], w2f[2][4];
#pragma unroll
    for (int ct = 0; ct < 2; ct++) {
        int col = colbase + ct * 16 + m16;
#pragma unroll
        for (int kc = 0; kc < 4; kc++) {
            w1f[ct][kc] = *(const bf16x8*)(W1t + (size_t)col * 128 + kc * 32 + k0);
            w2f[ct][kc] = *(const bf16x8*)(W2t + (size_t)col * 128 + kc * 32 + k0);
        }
    }
    f32x4 bs[2];
#pragma unroll
    for (int ct = 0; ct < 2; ct++)
        bs[ct] = *(const f32x4*)(bias + colbase + ct * 16 + quad * 4);

    float psum[2][4], psq[2][4];
#pragma unroll
    for (int ct = 0; ct < 2; ct++)
#pragma unroll
        for (int r = 0; r < 4; r++) { psum[ct][r] = 0.f; psq[ct][r] = 0.f; }

    for (int tile = blockIdx.x; tile < ntiles; tile += gridDim.x) {
        int grow = tile * 16 + srow;
        int beg = row_beg[grow];
        int end = row_end[grow];
        float idg = inv_deg[grow];
        bf16x8 own = *(const bf16x8*)(feat + (size_t)grow * 128 + sc0);

        float acc[8];
#pragma unroll
        for (int j = 0; j < 8; j++) acc[j] = 0.f;

        int e = beg;
        for (; e + 3 < end; e += 4) {
            int s0 = csr_src[e], s1 = csr_src[e + 1], s2 = csr_src[e + 2], s3 = csr_src[e + 3];
            bf16x8 v0 = *(const bf16x8*)(feat + (size_t)s0 * 128 + sc0);
            bf16x8 v1 = *(const bf16x8*)(feat + (size_t)s1 * 128 + sc0);
            bf16x8 v2 = *(const bf16x8*)(feat + (size_t)s2 * 128 + sc0);
            bf16x8 v3 = *(const bf16x8*)(feat + (size_t)s3 * 128 + sc0);
#pragma unroll
            for (int j = 0; j < 8; j++) {
                float t0 = fmaxf(b2f((unsigned short)v0[j]) * cc[j] + ss[j], 0.f);
                float t1 = fmaxf(b2f((unsigned short)v1[j]) * cc[j] + ss[j], 0.f);
                float t2 = fmaxf(b2f((unsigned short)v2[j]) * cc[j] + ss[j], 0.f);
                float t3 = fmaxf(b2f((unsigned short)v3[j]) * cc[j] + ss[j], 0.f);
                acc[j] += (t0 + t1) + (t2 + t3);
            }
        }
        for (; e < end; e++) {
            int s0 = csr_src[e];
            bf16x8 v0 = *(const bf16x8*)(feat + (size_t)s0 * 128 + sc0);
#pragma unroll
            for (int j = 0; j < 8; j++)
                acc[j] += fmaxf(b2f((unsigned short)v0[j]) * cc[j] + ss[j], 0.f);
        }

        __syncthreads();   // previous tile's LDS reads complete
        bf16x8 o1, o2;
#pragma unroll
        for (int j = 0; j < 8; j++) {
            o1[j] = (short)f2b(acc[j] * idg);
            o2[j] = (short)f2b(fmaxf(b2f((unsigned short)own[j]) * cc[j] + ss[j], 0.f));
        }
        *(bf16x8*)&As1[srow][sc0] = o1;
        *(bf16x8*)&As2[srow][sc0] = o2;
        __syncthreads();

        bf16x8 a1[4], a2[4];
#pragma unroll
        for (int kc = 0; kc < 4; kc++) {
            a1[kc] = *(const bf16x8*)&As1[m16][kc * 32 + k0];
            a2[kc] = *(const bf16x8*)&As2[m16][kc * 32 + k0];
        }
        f32x4 acc2[2];
        acc2[0] = (f32x4){0.f, 0.f, 0.f, 0.f};
        acc2[1] = (f32x4){0.f, 0.f, 0.f, 0.f};
#pragma unroll
        for (int kc = 0; kc < 4; kc++) {
#pragma unroll
            for (int ct = 0; ct < 2; ct++) {
                acc2[ct] = __builtin_amdgcn_mfma_f32_16x16x32_bf16(w1f[ct][kc], a1[kc], acc2[ct], 0, 0, 0);
                acc2[ct] = __builtin_amdgcn_mfma_f32_16x16x32_bf16(w2f[ct][kc], a2[kc], acc2[ct], 0, 0, 0);
            }
        }

        int orow = tile * 16 + m16;
#pragma unroll
        for (int ct = 0; ct < 2; ct++) {
            f32x4 v = acc2[ct] + bs[ct];
            int col = colbase + ct * 16 + quad * 4;
#pragma unroll
            for (int r = 0; r < 4; r++) { psum[ct][r] += v[r]; psq[ct][r] += v[r] * v[r]; }
            ushort4 u;
            u.x = f2b(v[0]); u.y = f2b(v[1]); u.z = f2b(v[2]); u.w = f2b(v[3]);
            *(ushort4*)(Cb + (size_t)orow * 128 + col) = u;
        }
    }

#pragma unroll
    for (int ct = 0; ct < 2; ct++)
#pragma unroll
        for (int r = 0; r < 4; r++) {
#pragma unroll
            for (int mask = 1; mask <= 8; mask <<= 1) {
                psum[ct][r] += __shfl_xor(psum[ct][r], mask, 64);
                psq[ct][r]  += __shfl_xor(psq[ct][r], mask, 64);
            }
        }
    __syncthreads();
    if (m16 == 0) {
#pragma unroll
        for (int ct = 0; ct < 2; ct++)
#pragma unroll
            for (int r = 0; r < 4; r++)
                red[colbase + ct * 16 + quad * 4 + r] = psum[ct][r];
    }
    __syncthreads();
    if (t < 128) atomicAdd(&stats_out[t], red[t]);
    __syncthreads();
    if (m16 == 0) {
#pragma unroll
        for (int ct = 0; ct < 2; ct++)
#pragma unroll
            for (int r = 0; r < 4; r++)
                red[colbase + ct * 16 + quad * 4 + r] = psq[ct][r];
    }
    __syncthreads();
    if (t < 128) atomicAdd(&stats_out[128 + t], red[t]);
}

// ---------------------------------------------------------------------------
// global mean pool: BN affine from stats, relu, mean (2x row unroll)
// ---------------------------------------------------------------------------
__global__ __launch_bounds__(128) void pool_mean_kernel(const unsigned short* __restrict__ h,
                                                        const int* __restrict__ gstart,
                                                        const float* __restrict__ stats,
                                                        const float* __restrict__ gamma,
                                                        const float* __restrict__ beta,
                                                        float* __restrict__ out) {
    int g = blockIdx.x;
    int col = threadIdx.x;
    float mu = stats[col] * INV_N;
    float var = stats[128 + col] * INV_N - mu * mu;
    float rs = rsqrtf(var + BN_EPS);
    float c = gamma[col] * rs;
    float b = beta[col] - mu * c;
    int beg = gstart[g];
    int end = gstart[g + 1];
    float s = 0.f;
    int i = beg;
    for (; i + 1 < end; i += 2) {
        float v0 = b2f(h[(size_t)i * 128 + col]);
        float v1 = b2f(h[(size_t)(i + 1) * 128 + col]);
        s += fmaxf(v0 * c + b, 0.f) + fmaxf(v1 * c + b, 0.f);
    }
    if (i < end)
        s += fmaxf(b2f(h[(size_t)i * 128 + col]) * c + b, 0.f);
    float cnt = fmaxf((float)(end - beg), 1.0f);
    out[(size_t)g * 128 + col] = s / cnt;
}

// ---------------------------------------------------------------------------
extern "C" void kernel_launch(void* const* d_in, const int* in_sizes, int n_in,
                              void* d_out, int out_size, void* d_ws, size_t ws_size,
                              hipStream_t stream) {
    const float* x    = (const float*)d_in[0];
    const int*   ei   = (const int*)d_in[1];
    const int*   src  = ei;
    const int*   dst  = ei + N_EDGES;
    const int*   batch = (const int*)d_in[2];
    const float* gw1  = (const float*)d_in[3];
    const float* gb1  = (const float*)d_in[4];
    const float* gw2  = (const float*)d_in[5];
    const float* gb2  = (const float*)d_in[6];
    const float* swl  = (const float*)d_in[7];
    const float* sbl  = (const float*)d_in[8];
    const float* swr  = (const float*)d_in[9];
    const float* bng  = (const float*)d_in[10];
    const float* bnb  = (const float*)d_in[11];
    float* out = (float*)d_out;

    // workspace layout (float units; bf16 buffers 16B-aligned)
    float* ws = (float*)d_ws;
    unsigned short* x16    = (unsigned short*)(ws + 0);         // 6.4M u16
    unsigned short* hpreA  = (unsigned short*)(ws + 3200000);   // 6.4M u16
    unsigned short* hpreB  = (unsigned short*)(ws + 6400000);   // 6.4M u16
    unsigned short* wt     = (unsigned short*)(ws + 9600000);   // 6*16384 u16
    float*          inv_deg= ws + 9650000;                      // 50000
    int*            row_beg= (int*)(ws + 9700000);              // 50000
    int*            cursor = (int*)(ws + 9750000);              // 50000 | total | stats(768)
    int*            total  = cursor + 50000;
    float*          stats  = (float*)(cursor + 50001);          // 3*256
    int*            csr_src= (int*)(ws + 9900000);              // 600000
    int*            gstart = (int*)(ws + 10500000);             // 513

    const int ntiles16 = N_NODES / 16;                          // 3125 exact
    const int fgrid = 1024;

    // ---- init: cursor + total + stats in one memset ----
    hipMemsetAsync(cursor, 0, (50001 + 768) * sizeof(int), stream);

    // ---- prep: x->bf16, weights->bf16^T, degree count ----
    prep_kernel<<<CONVX_BLOCKS + WCONV_BLOCKS + DEG_BLOCKS, 256, 0, stream>>>(
        x, gw1, gw2, swl, swr, dst, x16, wt, cursor);

    // ---- CSR ----
    alloc_kernel<<<ALLOC_BLOCKS + 3, 256, 0, stream>>>(cursor, row_beg, inv_deg, total, batch, gstart);
    csr_fill_kernel<<<(N_EDGES + 255) / 256, 256, 0, stream>>>(src, dst, cursor, csr_src, N_EDGES);

    // ---- GIN (fused gather + 2 GEMMs) -> hpreA, stats0 ----
    gin_fused_kernel<<<fgrid, 256, 0, stream>>>(
        x16, row_beg, cursor, csr_src, wt + 0 * 16384, wt + 1 * 16384,
        gb1, gb2, stats + 0, hpreA, ntiles16);

    // ---- SAGE 0 (fused) -> hpreB, stats1 ----
    sage_fused_kernel<<<fgrid, 256, 0, stream>>>(
        hpreA, row_beg, cursor, csr_src, stats + 0, bng + 0 * HID, bnb + 0 * HID, inv_deg,
        wt + 2 * 16384, wt + 3 * 16384, sbl + 0 * HID, stats + 256, hpreB, ntiles16);

    // ---- SAGE 1 (fused) -> hpreA, stats2 ----
    sage_fused_kernel<<<fgrid, 256, 0, stream>>>(
        hpreB, row_beg, cursor, csr_src, stats + 256, bng + 1 * HID, bnb + 1 * HID, inv_deg,
        wt + 4 * 16384, wt + 5 * 16384, sbl + 1 * HID, stats + 512, hpreA, ntiles16);

    // ---- pool (BN2 affine folded) ----
    pool_mean_kernel<<<N_GRAPHS, 128, 0, stream>>>(
        hpreA, gstart, stats + 512, bng + 2 * HID, bnb + 2 * HID, out);
}

// Round 14
// 367.522 us; speedup vs baseline: 1.0990x; 1.0990x over previous
//
#include <hip/hip_runtime.h>

#define N_NODES 50000
#define N_EDGES 600000
#define HID 128
#define N_GRAPHS 512
#define BN_EPS 1e-5f
#define INV_N (1.0f / 50000.0f)

typedef __attribute__((ext_vector_type(8))) short bf16x8;
typedef __attribute__((ext_vector_type(4))) float f32x4;

__device__ __forceinline__ unsigned short f2b(float f) {
    unsigned u = __float_as_uint(f);
    return (unsigned short)((u + 0x7FFFu + ((u >> 16) & 1u)) >> 16);
}
__device__ __forceinline__ float b2f(unsigned short h) {
    return __uint_as_float(((unsigned)h) << 16);
}

// ---------------------------------------------------------------------------
// prep: convert x -> bf16 | transpose+convert 6 weight mats | degree count
// ---------------------------------------------------------------------------
#define CONVX_BLOCKS 6250
#define WCONV_BLOCKS 384
#define DEG_BLOCKS   2344
__global__ __launch_bounds__(256) void prep_kernel(
    const float* __restrict__ x, const float* __restrict__ gw1, const float* __restrict__ gw2,
    const float* __restrict__ swl, const float* __restrict__ swr, const int* __restrict__ dst,
    unsigned short* __restrict__ x16, unsigned short* __restrict__ wt, int* __restrict__ deg)
{
    int b = blockIdx.x;
    int t = threadIdx.x;
    if (b < CONVX_BLOCKS) {
        int gid = b * 256 + t;
        int i = gid >> 5, l = gid & 31;
        if (i >= N_NODES) return;
        int c0 = l * 4;
        float4 v = *(const float4*)(x + (size_t)i * 128 + c0);
        ushort4 o;
        o.x = f2b(v.x); o.y = f2b(v.y); o.z = f2b(v.z); o.w = f2b(v.w);
        *(ushort4*)(x16 + (size_t)i * 128 + c0) = o;
    } else if (b < CONVX_BLOCKS + WCONV_BLOCKS) {
        int gid = (b - CONVX_BLOCKS) * 256 + t;   // < 6*16384
        int m = gid >> 14;
        int e = gid & 16383;
        int k = e >> 7;
        int n = e & 127;
        const float* src = (m == 0) ? gw1 : (m == 1) ? gw2 : (m == 2) ? swl
                         : (m == 3) ? swr : (m == 4) ? (swl + 16384) : (swr + 16384);
        wt[m * 16384 + n * 128 + k] = f2b(src[k * 128 + n]);
    } else {
        int e = (b - CONVX_BLOCKS - WCONV_BLOCKS) * 256 + t;
        if (e < N_EDGES) atomicAdd(&deg[dst[e]], 1);
    }
}

// ---------------------------------------------------------------------------
// alloc (per-block scan + atomic base) + gstart (binary search), fused
// ---------------------------------------------------------------------------
#define ALLOC_BLOCKS 196
__global__ __launch_bounds__(256) void alloc_kernel(int* __restrict__ cursor,
                                                    int* __restrict__ row_beg,
                                                    float* __restrict__ inv_deg,
                                                    int* __restrict__ total,
                                                    const int* __restrict__ batch,
                                                    int* __restrict__ gstart) {
    if (blockIdx.x >= ALLOC_BLOCKS) {
        int g = (blockIdx.x - ALLOC_BLOCKS) * 256 + threadIdx.x;
        if (g > N_GRAPHS) return;
        int lo = 0, hi = N_NODES;
        while (lo < hi) {
            int mid = (lo + hi) >> 1;
            if (batch[mid] < g) lo = mid + 1; else hi = mid;
        }
        gstart[g] = lo;
        return;
    }
    __shared__ int tmp[256];
    __shared__ int base;
    int i = blockIdx.x * 256 + threadIdx.x;
    int d = (i < N_NODES) ? cursor[i] : 0;
    tmp[threadIdx.x] = d;
    __syncthreads();
#pragma unroll
    for (int off = 1; off < 256; off <<= 1) {
        int v = (threadIdx.x >= off) ? tmp[threadIdx.x - off] : 0;
        __syncthreads();
        tmp[threadIdx.x] += v;
        __syncthreads();
    }
    if (threadIdx.x == 255) base = atomicAdd(total, tmp[255]);
    __syncthreads();
    if (i < N_NODES) {
        int b = base + tmp[threadIdx.x] - d;
        row_beg[i] = b;
        cursor[i] = b;
        inv_deg[i] = 1.0f / fmaxf((float)d, 1.0f);
    }
}

__global__ void csr_fill_kernel(const int* __restrict__ src, const int* __restrict__ dst,
                                int* __restrict__ cursor, int* __restrict__ csr_src, int nE) {
    int e = blockIdx.x * blockDim.x + threadIdx.x;
    if (e < nE) {
        int pos = atomicAdd(&cursor[dst[e]], 1);
        csr_src[pos] = src[e];
    }
}

// ---------------------------------------------------------------------------
// aggregate: agg[i] = (sum_e act(feat[src[e]])) * (MEAN? inv_deg : 1)
// AFF: act(v) = relu(v*c+s), affine computed in-kernel from stats
// HACT: also write hact[i] = act(feat[i])
// 16 lanes per node, bf16x8 (16B) loads, 4x edge unroll
// ---------------------------------------------------------------------------
template<bool AFF, bool MEAN, bool HACT>
__global__ __launch_bounds__(256) void aggregate_kernel(
    const unsigned short* __restrict__ feat,
    const int* __restrict__ row_beg, const int* __restrict__ row_end,
    const int* __restrict__ csr_src,
    const float* __restrict__ stats, const float* __restrict__ gamma,
    const float* __restrict__ beta, const float* __restrict__ inv_deg,
    unsigned short* __restrict__ agg, unsigned short* __restrict__ hact, int n)
{
    int gid = blockIdx.x * blockDim.x + threadIdx.x;
    int node = gid >> 4;
    int lane = gid & 15;
    if (node >= n) return;
    int c0 = lane * 8;

    float cc[8], ss[8];
    if (AFF) {
#pragma unroll
        for (int j = 0; j < 8; j++) {
            int col = c0 + j;
            float mu = stats[col] * INV_N;
            float var = stats[128 + col] * INV_N - mu * mu;
            float rs = rsqrtf(var + BN_EPS);
            float c = gamma[col] * rs;
            cc[j] = c;
            ss[j] = beta[col] - mu * c;
        }
    }

    float a[8];
#pragma unroll
    for (int j = 0; j < 8; j++) a[j] = 0.f;

    int beg = row_beg[node];
    int end = row_end[node];
    int e = beg;
    for (; e + 3 < end; e += 4) {
        int s0 = csr_src[e];
        int s1 = csr_src[e + 1];
        int s2 = csr_src[e + 2];
        int s3 = csr_src[e + 3];
        bf16x8 v0 = *(const bf16x8*)(feat + (size_t)s0 * 128 + c0);
        bf16x8 v1 = *(const bf16x8*)(feat + (size_t)s1 * 128 + c0);
        bf16x8 v2 = *(const bf16x8*)(feat + (size_t)s2 * 128 + c0);
        bf16x8 v3 = *(const bf16x8*)(feat + (size_t)s3 * 128 + c0);
#pragma unroll
        for (int j = 0; j < 8; j++) {
            float t0 = b2f((unsigned short)v0[j]);
            float t1 = b2f((unsigned short)v1[j]);
            float t2 = b2f((unsigned short)v2[j]);
            float t3 = b2f((unsigned short)v3[j]);
            if (AFF) {
                t0 = fmaxf(t0 * cc[j] + ss[j], 0.f);
                t1 = fmaxf(t1 * cc[j] + ss[j], 0.f);
                t2 = fmaxf(t2 * cc[j] + ss[j], 0.f);
                t3 = fmaxf(t3 * cc[j] + ss[j], 0.f);
            }
            a[j] += (t0 + t1) + (t2 + t3);
        }
    }
    for (; e < end; e++) {
        int s0 = csr_src[e];
        bf16x8 v0 = *(const bf16x8*)(feat + (size_t)s0 * 128 + c0);
#pragma unroll
        for (int j = 0; j < 8; j++) {
            float t0 = b2f((unsigned short)v0[j]);
            if (AFF) t0 = fmaxf(t0 * cc[j] + ss[j], 0.f);
            a[j] += t0;
        }
    }

    if (MEAN) {
        float s = inv_deg[node];
#pragma unroll
        for (int j = 0; j < 8; j++) a[j] *= s;
    }
    bf16x8 o;
#pragma unroll
    for (int j = 0; j < 8; j++) o[j] = (short)f2b(a[j]);
    *(bf16x8*)(agg + (size_t)node * 128 + c0) = o;

    if (HACT) {
        bf16x8 v = *(const bf16x8*)(feat + (size_t)node * 128 + c0);
        bf16x8 h;
#pragma unroll
        for (int j = 0; j < 8; j++)
            h[j] = (short)f2b(fmaxf(b2f((unsigned short)v[j]) * cc[j] + ss[j], 0.f));
        *(bf16x8*)(hact + (size_t)node * 128 + c0) = h;
    }
}

// ---------------------------------------------------------------------------
// Fused GIN GEMM: Cb = bf16( relu((X+AGG)@W1 + b1) @ W2 + b2 ), stats fp32.
// Both W1,W2 register-stationary; T1 round-trips through a 32x136 LDS tile.
// Swapped-operand MFMA: thread owns node row m16, weight cols colbase+ct*16+quad*4..+3.
// ---------------------------------------------------------------------------
__global__ __launch_bounds__(256, 2) void gemm_gin_kernel(
    const unsigned short* __restrict__ X, const unsigned short* __restrict__ AGG,
    const unsigned short* __restrict__ W1t, const unsigned short* __restrict__ W2t,
    const float* __restrict__ b1, const float* __restrict__ b2,
    float* __restrict__ stats, unsigned short* __restrict__ Cb,
    int M, int ntiles)
{
    __shared__ unsigned short t1[32][136];
    __shared__ float red[2][128];

    const int t = threadIdx.x;
    const int wave = t >> 6;
    const int lane = t & 63;
    const int colhalf = wave & 1;
    const int rowpair = wave >> 1;
    const int m16 = lane & 15;
    const int quad = lane >> 4;
    const int k0 = quad * 8;
    const int colbase = colhalf * 64;
    const int lrow = rowpair * 16 + m16;

    const bf16x8 zero8 = {0, 0, 0, 0, 0, 0, 0, 0};

    bf16x8 w1f[4][4], w2f[4][4];
#pragma unroll
    for (int ct = 0; ct < 4; ct++) {
        int col = colbase + ct * 16 + m16;
#pragma unroll
        for (int kc = 0; kc < 4; kc++) {
            w1f[ct][kc] = *(const bf16x8*)(W1t + (size_t)col * 128 + kc * 32 + k0);
            w2f[ct][kc] = *(const bf16x8*)(W2t + (size_t)col * 128 + kc * 32 + k0);
        }
    }
    f32x4 bs1[4], bs2[4];
#pragma unroll
    for (int ct = 0; ct < 4; ct++) {
        bs1[ct] = *(const f32x4*)(b1 + colbase + ct * 16 + quad * 4);
        bs2[ct] = *(const f32x4*)(b2 + colbase + ct * 16 + quad * 4);
    }

    float psum[4][4], psq[4][4];
#pragma unroll
    for (int ct = 0; ct < 4; ct++)
#pragma unroll
        for (int r = 0; r < 4; r++) { psum[ct][r] = 0.f; psq[ct][r] = 0.f; }

    for (int tile = blockIdx.x; tile < ntiles; tile += gridDim.x) {
        int arow = tile * 32 + rowpair * 16 + m16;
        bool aok = arow < M;

        // A = bf16(x + agg)
        bf16x8 a[4];
#pragma unroll
        for (int kc = 0; kc < 4; kc++) {
            if (aok) {
                bf16x8 vx = *(const bf16x8*)(X + (size_t)arow * 128 + kc * 32 + k0);
                bf16x8 vg = *(const bf16x8*)(AGG + (size_t)arow * 128 + kc * 32 + k0);
                bf16x8 r;
#pragma unroll
                for (int i = 0; i < 8; i++)
                    r[i] = (short)f2b(b2f((unsigned short)vx[i]) + b2f((unsigned short)vg[i]));
                a[kc] = r;
            } else {
                a[kc] = zero8;
            }
        }

        // phase 1
        f32x4 acc[4];
#pragma unroll
        for (int ct = 0; ct < 4; ct++) acc[ct] = (f32x4){0.f, 0.f, 0.f, 0.f};
#pragma unroll
        for (int kc = 0; kc < 4; kc++)
#pragma unroll
            for (int ct = 0; ct < 4; ct++)
                acc[ct] = __builtin_amdgcn_mfma_f32_16x16x32_bf16(w1f[ct][kc], a[kc], acc[ct], 0, 0, 0);

        // T1 = relu(acc + b1) -> LDS
        __syncthreads();   // previous tile's t1 reads complete
#pragma unroll
        for (int ct = 0; ct < 4; ct++) {
            f32x4 v = acc[ct] + bs1[ct];
            ushort4 o;
            o.x = f2b(fmaxf(v[0], 0.f));
            o.y = f2b(fmaxf(v[1], 0.f));
            o.z = f2b(fmaxf(v[2], 0.f));
            o.w = f2b(fmaxf(v[3], 0.f));
            *(ushort4*)&t1[lrow][colbase + ct * 16 + quad * 4] = o;
        }
        __syncthreads();

        // phase 2: A-frags from LDS
        bf16x8 ta[4];
#pragma unroll
        for (int kc = 0; kc < 4; kc++)
            ta[kc] = *(const bf16x8*)&t1[lrow][kc * 32 + k0];

        f32x4 acc2[4];
#pragma unroll
        for (int ct = 0; ct < 4; ct++) acc2[ct] = (f32x4){0.f, 0.f, 0.f, 0.f};
#pragma unroll
        for (int kc = 0; kc < 4; kc++)
#pragma unroll
            for (int ct = 0; ct < 4; ct++)
                acc2[ct] = __builtin_amdgcn_mfma_f32_16x16x32_bf16(w2f[ct][kc], ta[kc], acc2[ct], 0, 0, 0);

        int orow = arow;
        if (orow < M) {
#pragma unroll
            for (int ct = 0; ct < 4; ct++) {
                f32x4 v = acc2[ct] + bs2[ct];
                int col = colbase + ct * 16 + quad * 4;
#pragma unroll
                for (int r = 0; r < 4; r++) { psum[ct][r] += v[r]; psq[ct][r] += v[r] * v[r]; }
                ushort4 o;
                o.x = f2b(v[0]); o.y = f2b(v[1]); o.z = f2b(v[2]); o.w = f2b(v[3]);
                *(ushort4*)(Cb + (size_t)orow * 128 + col) = o;
            }
        }
    }

    // stats flush
#pragma unroll
    for (int ct = 0; ct < 4; ct++)
#pragma unroll
        for (int r = 0; r < 4; r++) {
#pragma unroll
            for (int mask = 1; mask <= 8; mask <<= 1) {
                psum[ct][r] += __shfl_xor(psum[ct][r], mask, 64);
                psq[ct][r]  += __shfl_xor(psq[ct][r], mask, 64);
            }
        }
    __syncthreads();
    if (m16 == 0) {
#pragma unroll
        for (int ct = 0; ct < 4; ct++)
#pragma unroll
            for (int r = 0; r < 4; r++)
                red[rowpair][colbase + ct * 16 + quad * 4 + r] = psum[ct][r];
    }
    __syncthreads();
    if (t < 128) atomicAdd(&stats[t], red[0][t] + red[1][t]);
    __syncthreads();
    if (m16 == 0) {
#pragma unroll
        for (int ct = 0; ct < 4; ct++)
#pragma unroll
            for (int r = 0; r < 4; r++)
                red[rowpair][colbase + ct * 16 + quad * 4 + r] = psq[ct][r];
    }
    __syncthreads();
    if (t < 128) atomicAdd(&stats[128 + t], red[0][t] + red[1][t]);
}

// ---------------------------------------------------------------------------
// Dual-matrix GEMM (SAGE): Cb = bf16(A1@W1 + A2@W2 + bias), stats fp32.
// ---------------------------------------------------------------------------
__global__ __launch_bounds__(256) void gemm_dual_kernel(
    const unsigned short* __restrict__ A1, const unsigned short* __restrict__ A2,
    const unsigned short* __restrict__ W1t, const unsigned short* __restrict__ W2t,
    const float* __restrict__ bias, float* __restrict__ stats,
    unsigned short* __restrict__ Cb, int M, int ntiles)
{
    __shared__ float red[128];

    const int t = threadIdx.x;
    const int wave = t >> 6;
    const int lane = t & 63;
    const int m16 = lane & 15;
    const int quad = lane >> 4;
    const int k0 = quad * 8;
    const int colbase = wave * 32;

    const bf16x8 zero8 = {0, 0, 0, 0, 0, 0, 0, 0};

    bf16x8 w1f[2][4], w2f[2][4];
#pragma unroll
    for (int ct = 0; ct < 2; ct++) {
        int col = colbase + ct * 16 + m16;
#pragma unroll
        for (int kc = 0; kc < 4; kc++) {
            w1f[ct][kc] = *(const bf16x8*)(W1t + (size_t)col * 128 + kc * 32 + k0);
            w2f[ct][kc] = *(const bf16x8*)(W2t + (size_t)col * 128 + kc * 32 + k0);
        }
    }
    f32x4 bs[2];
#pragma unroll
    for (int ct = 0; ct < 2; ct++)
        bs[ct] = *(const f32x4*)(bias + colbase + ct * 16 + quad * 4);

    float psum[2][4], psq[2][4];
#pragma unroll
    for (int ct = 0; ct < 2; ct++)
#pragma unroll
        for (int r = 0; r < 4; r++) { psum[ct][r] = 0.f; psq[ct][r] = 0.f; }

    bf16x8 a1[4], a2[4], a1n[4], a2n[4];

    int tile = blockIdx.x;
    if (tile < ntiles) {
        int arow = tile * 16 + m16;
        bool aok = arow < M;
#pragma unroll
        for (int kc = 0; kc < 4; kc++) {
            a1[kc] = aok ? *(const bf16x8*)(A1 + (size_t)arow * 128 + kc * 32 + k0) : zero8;
            a2[kc] = aok ? *(const bf16x8*)(A2 + (size_t)arow * 128 + kc * 32 + k0) : zero8;
        }
    }

    for (; tile < ntiles; tile += gridDim.x) {
        int nt = tile + gridDim.x;
        if (nt < ntiles) {
            int arow = nt * 16 + m16;
            bool aok = arow < M;
#pragma unroll
            for (int kc = 0; kc < 4; kc++) {
                a1n[kc] = aok ? *(const bf16x8*)(A1 + (size_t)arow * 128 + kc * 32 + k0) : zero8;
                a2n[kc] = aok ? *(const bf16x8*)(A2 + (size_t)arow * 128 + kc * 32 + k0) : zero8;
            }
        }

        f32x4 acc[2];
        acc[0] = (f32x4){0.f, 0.f, 0.f, 0.f};
        acc[1] = (f32x4){0.f, 0.f, 0.f, 0.f};
#pragma unroll
        for (int kc = 0; kc < 4; kc++) {
#pragma unroll
            for (int ct = 0; ct < 2; ct++) {
                acc[ct] = __builtin_amdgcn_mfma_f32_16x16x32_bf16(w1f[ct][kc], a1[kc], acc[ct], 0, 0, 0);
                acc[ct] = __builtin_amdgcn_mfma_f32_16x16x32_bf16(w2f[ct][kc], a2[kc], acc[ct], 0, 0, 0);
            }
        }

        int orow = tile * 16 + m16;
        if (orow < M) {
#pragma unroll
            for (int ct = 0; ct < 2; ct++) {
                f32x4 v = acc[ct] + bs[ct];
                int col = colbase + ct * 16 + quad * 4;
#pragma unroll
                for (int r = 0; r < 4; r++) { psum[ct][r] += v[r]; psq[ct][r] += v[r] * v[r]; }
                ushort4 o;
                o.x = f2b(v[0]); o.y = f2b(v[1]); o.z = f2b(v[2]); o.w = f2b(v[3]);
                *(ushort4*)(Cb + (size_t)orow * 128 + col) = o;
            }
        }

        if (nt < ntiles) {
            a1[0] = a1n[0]; a1[1] = a1n[1]; a1[2] = a1n[2]; a1[3] = a1n[3];
            a2[0] = a2n[0]; a2[1] = a2n[1]; a2[2] = a2n[2]; a2[3] = a2n[3];
        }
    }

#pragma unroll
    for (int ct = 0; ct < 2; ct++)
#pragma unroll
        for (int r = 0; r < 4; r++) {
#pragma unroll
            for (int mask = 1; mask <= 8; mask <<= 1) {
                psum[ct][r] += __shfl_xor(psum[ct][r], mask, 64);
                psq[ct][r]  += __shfl_xor(psq[ct][r], mask, 64);
            }
        }
    if (m16 == 0) {
#pragma unroll
        for (int ct = 0; ct < 2; ct++)
#pragma unroll
            for (int r = 0; r < 4; r++)
                red[colbase + ct * 16 + quad * 4 + r] = psum[ct][r];
    }
    __syncthreads();
    if (t < 128) atomicAdd(&stats[t], red[t]);
    __syncthreads();
    if (m16 == 0) {
#pragma unroll
        for (int ct = 0; ct < 2; ct++)
#pragma unroll
            for (int r = 0; r < 4; r++)
                red[colbase + ct * 16 + quad * 4 + r] = psq[ct][r];
    }
    __syncthreads();
    if (t < 128) atomicAdd(&stats[128 + t], red[t]);
}

// ---------------------------------------------------------------------------
// global mean pool: BN affine from stats, relu, mean.
// 256 threads: 2 rows per iteration (t>>7) + LDS reduction.
// ---------------------------------------------------------------------------
__global__ __launch_bounds__(256) void pool_mean_kernel(const unsigned short* __restrict__ h,
                                                        const int* __restrict__ gstart,
                                                        const float* __restrict__ stats,
                                                        const float* __restrict__ gamma,
                                                        const float* __restrict__ beta,
                                                        float* __restrict__ out) {
    __shared__ float red[256];
    int g = blockIdx.x;
    int t = threadIdx.x;
    int col = t & 127;
    int half = t >> 7;
    float mu = stats[col] * INV_N;
    float var = stats[128 + col] * INV_N - mu * mu;
    float rs = rsqrtf(var + BN_EPS);
    float c = gamma[col] * rs;
    float b = beta[col] - mu * c;
    int beg = gstart[g];
    int end = gstart[g + 1];
    float s = 0.f;
    for (int i = beg + half; i < end; i += 2)
        s += fmaxf(b2f(h[(size_t)i * 128 + col]) * c + b, 0.f);
    red[t] = s;
    __syncthreads();
    if (t < 128) {
        float cnt = fmaxf((float)(end - beg), 1.0f);
        out[(size_t)g * 128 + t] = (red[t] + red[128 + t]) / cnt;
    }
}

// ---------------------------------------------------------------------------
extern "C" void kernel_launch(void* const* d_in, const int* in_sizes, int n_in,
                              void* d_out, int out_size, void* d_ws, size_t ws_size,
                              hipStream_t stream) {
    const float* x    = (const float*)d_in[0];
    const int*   ei   = (const int*)d_in[1];
    const int*   src  = ei;
    const int*   dst  = ei + N_EDGES;
    const int*   batch = (const int*)d_in[2];
    const float* gw1  = (const float*)d_in[3];
    const float* gb1  = (const float*)d_in[4];
    const float* gw2  = (const float*)d_in[5];
    const float* gb2  = (const float*)d_in[6];
    const float* swl  = (const float*)d_in[7];
    const float* sbl  = (const float*)d_in[8];
    const float* swr  = (const float*)d_in[9];
    const float* bng  = (const float*)d_in[10];
    const float* bnb  = (const float*)d_in[11];
    float* out = (float*)d_out;

    // workspace layout (float units; bf16 buffers 16B-aligned)
    float* ws = (float*)d_ws;
    unsigned short* x16    = (unsigned short*)(ws + 0);
    unsigned short* agg16  = (unsigned short*)(ws + 3200000);
    unsigned short* hact16 = (unsigned short*)(ws + 6400000);
    unsigned short* hpre16 = (unsigned short*)(ws + 9600000);
    unsigned short* wt     = (unsigned short*)(ws + 12800000);  // 6*16384 u16
    float*          inv_deg= ws + 12850000;                     // 50000
    int*            row_beg= (int*)(ws + 12900000);             // 50000
    int*            cursor = (int*)(ws + 12950000);             // 50000 | total | stats(768)
    int*            total  = cursor + 50000;
    float*          stats  = (float*)(cursor + 50001);          // 3*256
    int*            csr_src= (int*)(ws + 13100000);             // 600000
    int*            gstart = (int*)(ws + 13700000);             // 513

    const int aggr_blocks = (N_NODES * 16 + 255) / 256;         // 3125
    const int ntiles32 = (N_NODES + 31) / 32;                   // 1563
    const int ntiles16 = (N_NODES + 15) / 16;                   // 3125
    const int ggrid = 512;

    // ---- init: cursor + total + stats in one memset ----
    hipMemsetAsync(cursor, 0, (50001 + 768) * sizeof(int), stream);

    // ---- prep: x->bf16, weights->bf16^T, degree count ----
    prep_kernel<<<CONVX_BLOCKS + WCONV_BLOCKS + DEG_BLOCKS, 256, 0, stream>>>(
        x, gw1, gw2, swl, swr, dst, x16, wt, cursor);

    // ---- CSR ----
    alloc_kernel<<<ALLOC_BLOCKS + 3, 256, 0, stream>>>(cursor, row_beg, inv_deg, total, batch, gstart);
    csr_fill_kernel<<<(N_EDGES + 255) / 256, 256, 0, stream>>>(src, dst, cursor, csr_src, N_EDGES);

    // ---- GIN ----
    aggregate_kernel<false, false, false><<<aggr_blocks, 256, 0, stream>>>(
        x16, row_beg, cursor, csr_src, nullptr, nullptr, nullptr, nullptr, agg16, nullptr, N_NODES);
    gemm_gin_kernel<<<ggrid, 256, 0, stream>>>(
        x16, agg16, wt + 0 * 16384, wt + 1 * 16384, gb1, gb2, stats + 0, hpre16, N_NODES, ntiles32);

    // ---- SAGE 0 ----
    aggregate_kernel<true, true, true><<<aggr_blocks, 256, 0, stream>>>(
        hpre16, row_beg, cursor, csr_src, stats + 0, bng + 0 * HID, bnb + 0 * HID, inv_deg,
        agg16, hact16, N_NODES);
    gemm_dual_kernel<<<ggrid, 256, 0, stream>>>(
        agg16, hact16, wt + 2 * 16384, wt + 3 * 16384, sbl + 0 * HID, stats + 256, hpre16, N_NODES, ntiles16);

    // ---- SAGE 1 ----
    aggregate_kernel<true, true, true><<<aggr_blocks, 256, 0, stream>>>(
        hpre16, row_beg, cursor, csr_src, stats + 256, bng + 1 * HID, bnb + 1 * HID, inv_deg,
        agg16, hact16, N_NODES);
    gemm_dual_kernel<<<ggrid, 256, 0, stream>>>(
        agg16, hact16, wt + 4 * 16384, wt + 5 * 16384, sbl + 1 * HID, stats + 512, hpre16, N_NODES, ntiles16);

    // ---- pool (BN2 affine folded) ----
    pool_mean_kernel<<<N_GRAPHS, 256, 0, stream>>>(
        hpre16, gstart, stats + 512, bng + 2 * HID, bnb + 2 * HID, out);
}